// Round 1
// baseline (2122.220 us; speedup 1.0000x reference)
//
#include <hip/hip_runtime.h>

// Mixed2DEpsNetwork: G=2000 graphs x 16 nodes, H=128, 6 EGNN layers + edge MLP.
// Strategy: factor edge GEMMs through per-node transforms, precompute bond-type
// tables, fuse the entire 6-layer encoder into one per-graph block (LDS-resident h).

#define G_GRAPHS 2000
#define NPG 16
#define HID 128
#define FDIM 28
#define NLAYER 6
#define NNODES 32000
#define EL_PER_G 32
#define EG_PER_G 240
#define EL_TOT (G_GRAPHS*EL_PER_G)
#define EG_TOT (G_GRAPHS*EG_PER_G)
#define TMAX 32   // bond-type table size (actual types are 0..21)

__device__ __forceinline__ float silu_f(float x) {
    return x / (1.0f + __expf(-x));
}
__device__ __forceinline__ int clampT(int t) {
    return t < 0 ? 0 : (t > TMAX-1 ? TMAX-1 : t);
}

// bondA[l][t][c] = bond_emb[t] @ Wl[l,256:384] + bl[l]   (e_r contribution, bl folded)
// bondB[l][t][c] = bond_emb[t] @ Wl[l,384:512]           (e_p contribution)
__global__ void __launch_bounds__(HID) k_tab_bond(
    const float* __restrict__ bond_emb, const float* __restrict__ Wl,
    const float* __restrict__ bl, float* __restrict__ bondA, float* __restrict__ bondB)
{
    int l = blockIdx.x >> 5;
    int t = blockIdx.x & 31;
    int c = threadIdx.x;
    const float* WlL = Wl + (size_t)l*512*HID;
    float accA = bl[l*HID + c];
    float accB = 0.f;
    #pragma unroll 4
    for (int k = 0; k < HID; k++) {
        float e = bond_emb[t*HID + k];
        accA = fmaf(e, WlL[(256+k)*HID + c], accA);
        accB = fmaf(e, WlL[(384+k)*HID + c], accB);
    }
    bondA[(l*TMAX + t)*HID + c] = accA;
    bondB[(l*TMAX + t)*HID + c] = accB;
}

// pairT[tr][tp][c] = (bond_emb[tr]*bond_emb[tp]) @ W0[128:256] + b0  (b0 folded)
__global__ void __launch_bounds__(HID) k_tab_pair(
    const float* __restrict__ bond_emb, const float* __restrict__ W0,
    const float* __restrict__ b0, float* __restrict__ pairT)
{
    int tr = blockIdx.x >> 5;
    int tp = blockIdx.x & 31;
    int c = threadIdx.x;
    float acc = b0[c];
    #pragma unroll 4
    for (int k = 0; k < HID; k++)
        acc = fmaf(bond_emb[tr*HID + k] * bond_emb[tp*HID + k], W0[(HID+k)*HID + c], acc);
    pairT[(size_t)blockIdx.x*HID + c] = acc;
}

// h[n] = concat(atom_emb[at] + r@W, (p-r)@W)
__global__ void __launch_bounds__(256) k_init_h(
    const int* __restrict__ atom_type, const float* __restrict__ r_feat,
    const float* __restrict__ p_feat, const float* __restrict__ atom_emb,
    const float* __restrict__ afW, float* __restrict__ h)
{
    int n = blockIdx.x*4 + (threadIdx.x >> 6);
    int j = threadIdx.x & 63;
    int at = atom_type[n];
    float accr = 0.f, accp = 0.f;
    #pragma unroll
    for (int k = 0; k < FDIM; k++) {
        float w = afW[k*64 + j];
        accr = fmaf(r_feat[n*FDIM + k], w, accr);
        accp = fmaf(p_feat[n*FDIM + k], w, accp);
    }
    h[n*HID + j]      = atom_emb[at*64 + j] + accr;
    h[n*HID + 64 + j] = accp - accr;
}

// One block per graph; all 6 layers fused, h resident in LDS.
__global__ void __launch_bounds__(256) k_encoder(
    const float* __restrict__ pos,
    const int* __restrict__ eil, const int* __restrict__ etr, const int* __restrict__ etp,
    const int* __restrict__ eig,
    const float* __restrict__ Wg, const float* __restrict__ bg,
    const float* __restrict__ Wl,
    const float* __restrict__ Wn, const float* __restrict__ bn,
    const float* __restrict__ bondA, const float* __restrict__ bondB,
    float* __restrict__ h)
{
    __shared__ float h_s[NPG][HID];
    __shared__ float A_s[NPG][HID], B_s[NPG][HID], Al_s[NPG][HID], Bl_s[NPG][HID];
    __shared__ float agg_s[NPG][HID];
    __shared__ float d2_s[EG_PER_G];
    __shared__ float px[NPG], py[NPG], pz[NPG];
    __shared__ int gsl[EG_PER_G];
    __shared__ int glist[NPG][15];
    __shared__ int gcnt[NPG];
    __shared__ int llist[NPG][2];
    __shared__ int lcnt[NPG];
    __shared__ int lsrc[EL_PER_G], ltr[EL_PER_G], ltp[EL_PER_G];

    const int g = blockIdx.x;
    const int tid = threadIdx.x;
    const int c = tid & 127;
    const int half = tid >> 7;

    for (int idx = tid; idx < NPG*HID; idx += 256)
        h_s[idx >> 7][idx & 127] = h[(size_t)g*NPG*HID + idx];
    if (tid < NPG) {
        px[tid] = pos[(g*NPG + tid)*3 + 0];
        py[tid] = pos[(g*NPG + tid)*3 + 1];
        pz[tid] = pos[(g*NPG + tid)*3 + 2];
        gcnt[tid] = 0; lcnt[tid] = 0;
    }
    __syncthreads();
    if (tid < EG_PER_G) {
        int e = g*EG_PER_G + tid;
        int s = eig[e] - g*NPG;
        int d = eig[EG_TOT + e] - g*NPG;
        gsl[tid] = s;
        float dx = px[s]-px[d], dy = py[s]-py[d], dz = pz[s]-pz[d];
        d2_s[tid] = dx*dx + dy*dy + dz*dz;
        int slot = atomicAdd(&gcnt[d], 1);
        if (slot < 15) glist[d][slot] = tid;
    }
    if (tid < EL_PER_G) {
        int e = g*EL_PER_G + tid;
        int s = eil[e] - g*NPG;
        int d = eil[EL_TOT + e] - g*NPG;
        lsrc[tid] = s;
        ltr[tid] = clampT(etr[e]);
        ltp[tid] = clampT(etp[e]);
        int slot = atomicAdd(&lcnt[d], 1);
        if (slot < 2) llist[d][slot] = tid;
    }
    __syncthreads();

    for (int l = 0; l < NLAYER; l++) {
        const float* WgL = Wg + (size_t)l*257*HID;
        const float* WlL = Wl + (size_t)l*512*HID;
        const float* WnL = Wn + (size_t)l*256*HID;

        // ---- phase 1: A=h@Wg0, B=h@Wg1, Al=h@Wl0, Bl=h@Wl1  ([16,128]@[128,128] x4)
        float aA[8], aB[8], aAl[8], aBl[8];
        #pragma unroll
        for (int n8 = 0; n8 < 8; n8++) { aA[n8]=0.f; aB[n8]=0.f; aAl[n8]=0.f; aBl[n8]=0.f; }
        for (int k = 0; k < HID; k++) {
            float w0 = WgL[k*HID + c];
            float w1 = WgL[(HID+k)*HID + c];
            float w2 = WlL[k*HID + c];
            float w3 = WlL[(HID+k)*HID + c];
            #pragma unroll
            for (int n8 = 0; n8 < 8; n8++) {
                float hv = h_s[half*8 + n8][k];   // wave-uniform -> LDS broadcast
                aA[n8]  = fmaf(hv, w0, aA[n8]);
                aB[n8]  = fmaf(hv, w1, aB[n8]);
                aAl[n8] = fmaf(hv, w2, aAl[n8]);
                aBl[n8] = fmaf(hv, w3, aBl[n8]);
            }
        }
        #pragma unroll
        for (int n8 = 0; n8 < 8; n8++) {
            int n = half*8 + n8;
            A_s[n][c] = aA[n8]; B_s[n][c] = aB[n8];
            Al_s[n][c] = aAl[n8]; Bl_s[n][c] = aBl[n8];
        }
        float wgd = WgL[256*HID + c];
        float bgc = bg[l*HID + c];
        __syncthreads();

        // ---- phase 2: messages + per-dest accumulation (no atomics)
        const float* bA = bondA + (size_t)l*TMAX*HID;
        const float* bB = bondB + (size_t)l*TMAX*HID;
        #pragma unroll
        for (int n8 = 0; n8 < 8; n8++) {
            int d = half*8 + n8;
            float Bd  = B_s[d][c];
            float Bld = Bl_s[d][c];
            float acc = 0.f;
            int gc = gcnt[d] < 15 ? gcnt[d] : 15;
            for (int i = 0; i < gc; i++) {
                int et = glist[d][i];
                float x = A_s[gsl[et]][c] + Bd + d2_s[et]*wgd + bgc;
                acc += silu_f(x);
            }
            int lc = lcnt[d] < 2 ? lcnt[d] : 2;
            for (int i = 0; i < lc; i++) {
                int k = llist[d][i];
                float x = Al_s[lsrc[k]][c] + Bld + bA[ltr[k]*HID + c] + bB[ltp[k]*HID + c];
                acc += silu_f(x);
            }
            agg_s[d][c] = acc;
        }
        __syncthreads();

        // ---- phase 3: h += silu([h,agg]@Wn + bn)
        float u[8];
        #pragma unroll
        for (int n8 = 0; n8 < 8; n8++) u[n8] = 0.f;
        for (int k = 0; k < HID; k++) {
            float w0 = WnL[k*HID + c];
            float w1 = WnL[(HID+k)*HID + c];
            #pragma unroll
            for (int n8 = 0; n8 < 8; n8++) {
                int n = half*8 + n8;
                u[n8] = fmaf(h_s[n][k],  w0, u[n8]);
                u[n8] = fmaf(agg_s[n][k], w1, u[n8]);
            }
        }
        float bnc = bn[l*HID + c];
        #pragma unroll
        for (int n8 = 0; n8 < 8; n8++) u[n8] = silu_f(u[n8] + bnc);
        __syncthreads();   // ensure all phase-3 reads of h_s are done
        #pragma unroll
        for (int n8 = 0; n8 < 8; n8++) h_s[half*8 + n8][c] += u[n8];
        __syncthreads();
    }

    for (int idx = tid; idx < NPG*HID; idx += 256)
        h[(size_t)g*NPG*HID + idx] = h_s[idx >> 7][idx & 127];
}

// Edge MLP: x0=relu((h[s]*h[d])@W00 + pairT[tr][tp]); x1=relu(x0@W1+b1); out=x1@W2+b2
__global__ void __launch_bounds__(256) k_mlp(
    const float* __restrict__ h,
    const int* __restrict__ eig, const int* __restrict__ egr, const int* __restrict__ egp,
    const float* __restrict__ pairT, const float* __restrict__ W0,
    const float* __restrict__ W1, const float* __restrict__ b1,
    const float* __restrict__ W2, const float* __restrict__ b2,
    float* __restrict__ out)
{
    __shared__ float h_s[NPG][HID];
    __shared__ float prod[4][HID];
    __shared__ float x0_s[4][HID];
    __shared__ int sgl[EG_PER_G], dgl[EG_PER_G], pidx[EG_PER_G];

    const int g = blockIdx.x;
    const int tid = threadIdx.x;

    for (int idx = tid; idx < NPG*HID; idx += 256)
        h_s[idx >> 7][idx & 127] = h[(size_t)g*NPG*HID + idx];
    if (tid < EG_PER_G) {
        int e = g*EG_PER_G + tid;
        sgl[tid] = eig[e] - g*NPG;
        dgl[tid] = eig[EG_TOT + e] - g*NPG;
        pidx[tid] = clampT(egr[e])*TMAX + clampT(egp[e]);
    }
    __syncthreads();

    const int c = tid & 127;
    const int half = tid >> 7;
    const int j = tid & 63;
    const int q = tid >> 6;
    const float b2v = b2[0];

    for (int e0 = 0; e0 < EG_PER_G; e0 += 4) {
        for (int idx = tid; idx < 4*HID; idx += 256) {
            int qq = idx >> 7, k = idx & 127;
            int e = e0 + qq;
            prod[qq][k] = h_s[sgl[e]][k] * h_s[dgl[e]][k];
        }
        __syncthreads();
        {
            int qa = half*2, qb = qa + 1;
            float acca = pairT[(size_t)pidx[e0+qa]*HID + c];
            float accb = pairT[(size_t)pidx[e0+qb]*HID + c];
            for (int k = 0; k < HID; k++) {
                float w = W0[k*HID + c];          // W00 row k (coalesced, L1-hot)
                acca = fmaf(prod[qa][k], w, acca); // prod reads: wave-uniform broadcast
                accb = fmaf(prod[qb][k], w, accb);
            }
            x0_s[qa][c] = fmaxf(acca, 0.f);
            x0_s[qb][c] = fmaxf(accb, 0.f);
        }
        __syncthreads();
        {
            float acc = b1[j];
            for (int cc = 0; cc < HID; cc++)
                acc = fmaf(x0_s[q][cc], W1[cc*64 + j], acc);
            float v = fmaxf(acc, 0.f) * W2[j];
            #pragma unroll
            for (int off = 32; off > 0; off >>= 1)
                v += __shfl_down(v, off, 64);
            if (j == 0) out[(size_t)g*EG_PER_G + e0 + q] = v + b2v;
        }
        __syncthreads();
    }
}

extern "C" void kernel_launch(void* const* d_in, const int* in_sizes, int n_in,
                              void* d_out, int out_size, void* d_ws, size_t ws_size,
                              hipStream_t stream) {
    const int*   atom_type = (const int*)  d_in[0];
    const float* r_feat    = (const float*)d_in[1];
    const float* p_feat    = (const float*)d_in[2];
    const float* pos       = (const float*)d_in[3];
    const int*   eil       = (const int*)  d_in[4];
    const int*   etr       = (const int*)  d_in[5];
    const int*   etp       = (const int*)  d_in[6];
    const int*   eig       = (const int*)  d_in[7];
    const int*   egr       = (const int*)  d_in[8];
    const int*   egp       = (const int*)  d_in[9];
    const float* bond_emb  = (const float*)d_in[10];
    const float* atom_emb  = (const float*)d_in[11];
    const float* afW       = (const float*)d_in[12];
    const float* Wl        = (const float*)d_in[13];
    const float* bl        = (const float*)d_in[14];
    const float* Wg        = (const float*)d_in[15];
    const float* bg        = (const float*)d_in[16];
    const float* Wn        = (const float*)d_in[17];
    const float* bn        = (const float*)d_in[18];
    const float* W0        = (const float*)d_in[19];
    const float* b0        = (const float*)d_in[20];
    const float* W1        = (const float*)d_in[21];
    const float* b1        = (const float*)d_in[22];
    const float* W2        = (const float*)d_in[23];
    const float* b2        = (const float*)d_in[24];

    // workspace: h [N,128] + bond tables + pair table  (~17.1 MB)
    float* h     = (float*)d_ws;
    float* bondA = h + (size_t)NNODES*HID;
    float* bondB = bondA + (size_t)NLAYER*TMAX*HID;
    float* pairT = bondB + (size_t)NLAYER*TMAX*HID;
    float* out   = (float*)d_out;

    k_tab_bond<<<dim3(NLAYER*TMAX), dim3(HID), 0, stream>>>(bond_emb, Wl, bl, bondA, bondB);
    k_tab_pair<<<dim3(TMAX*TMAX),  dim3(HID), 0, stream>>>(bond_emb, W0, b0, pairT);
    k_init_h  <<<dim3(NNODES/4),   dim3(256), 0, stream>>>(atom_type, r_feat, p_feat, atom_emb, afW, h);
    k_encoder <<<dim3(G_GRAPHS),   dim3(256), 0, stream>>>(pos, eil, etr, etp, eig,
                                                           Wg, bg, Wl, Wn, bn, bondA, bondB, h);
    k_mlp     <<<dim3(G_GRAPHS),   dim3(256), 0, stream>>>(h, eig, egr, egp, pairT,
                                                           W0, W1, b1, W2, b2, out);
}

// Round 2
// 1786.128 us; speedup vs baseline: 1.1882x; 1.1882x over previous
//
#include <hip/hip_runtime.h>

// Mixed2DEpsNetwork: G=2000 graphs x 16 nodes, H=128, 6 EGNN layers + edge MLP.
// R2: fp32 restructure for FMA density — transposed LDS activations (broadcast
// b128 reads), float2 weight streams, dense adjacency mask, batched MLP.

#define G_GRAPHS 2000
#define NPG 16
#define HID 128
#define FDIM 28
#define NLAYER 6
#define NNODES 32000
#define EL_PER_G 32
#define EG_PER_G 240
#define EL_TOT (G_GRAPHS*EL_PER_G)
#define EG_TOT (G_GRAPHS*EG_PER_G)
#define TMAX 32   // bond-type table size (actual types are 0..21)

__device__ __forceinline__ float silu_f(float x) {
    return x / (1.0f + __expf(-x));
}
__device__ __forceinline__ int clampT(int t) {
    return t < 0 ? 0 : (t > TMAX-1 ? TMAX-1 : t);
}

// bondA[l][t][c] = bond_emb[t] @ Wl[l,256:384] + bl[l]   (e_r contribution, bl folded)
// bondB[l][t][c] = bond_emb[t] @ Wl[l,384:512]           (e_p contribution)
__global__ void __launch_bounds__(HID) k_tab_bond(
    const float* __restrict__ bond_emb, const float* __restrict__ Wl,
    const float* __restrict__ bl, float* __restrict__ bondA, float* __restrict__ bondB)
{
    int l = blockIdx.x >> 5;
    int t = blockIdx.x & 31;
    int c = threadIdx.x;
    const float* WlL = Wl + (size_t)l*512*HID;
    float accA = bl[l*HID + c];
    float accB = 0.f;
    #pragma unroll 4
    for (int k = 0; k < HID; k++) {
        float e = bond_emb[t*HID + k];
        accA = fmaf(e, WlL[(256+k)*HID + c], accA);
        accB = fmaf(e, WlL[(384+k)*HID + c], accB);
    }
    bondA[(l*TMAX + t)*HID + c] = accA;
    bondB[(l*TMAX + t)*HID + c] = accB;
}

// pairT[tr][tp][c] = (bond_emb[tr]*bond_emb[tp]) @ W0[128:256] + b0  (b0 folded)
__global__ void __launch_bounds__(HID) k_tab_pair(
    const float* __restrict__ bond_emb, const float* __restrict__ W0,
    const float* __restrict__ b0, float* __restrict__ pairT)
{
    int tr = blockIdx.x >> 5;
    int tp = blockIdx.x & 31;
    int c = threadIdx.x;
    float acc = b0[c];
    #pragma unroll 4
    for (int k = 0; k < HID; k++)
        acc = fmaf(bond_emb[tr*HID + k] * bond_emb[tp*HID + k], W0[(HID+k)*HID + c], acc);
    pairT[(size_t)blockIdx.x*HID + c] = acc;
}

// h[n] = concat(atom_emb[at] + r@W, (p-r)@W)
__global__ void __launch_bounds__(256) k_init_h(
    const int* __restrict__ atom_type, const float* __restrict__ r_feat,
    const float* __restrict__ p_feat, const float* __restrict__ atom_emb,
    const float* __restrict__ afW, float* __restrict__ h)
{
    int n = blockIdx.x*4 + (threadIdx.x >> 6);
    int j = threadIdx.x & 63;
    int at = atom_type[n];
    float accr = 0.f, accp = 0.f;
    #pragma unroll
    for (int k = 0; k < FDIM; k++) {
        float w = afW[k*64 + j];
        accr = fmaf(r_feat[n*FDIM + k], w, accr);
        accp = fmaf(p_feat[n*FDIM + k], w, accp);
    }
    h[n*HID + j]      = atom_emb[at*64 + j] + accr;
    h[n*HID + 64 + j] = accp - accr;
}

// One block per graph; all 6 layers fused, h transposed in LDS.
__global__ void __launch_bounds__(256) k_encoder(
    const float* __restrict__ pos,
    const int* __restrict__ eil, const int* __restrict__ etr, const int* __restrict__ etp,
    const int* __restrict__ eig,
    const float* __restrict__ Wg, const float* __restrict__ bg,
    const float* __restrict__ Wl,
    const float* __restrict__ Wn, const float* __restrict__ bn,
    const float* __restrict__ bondA, const float* __restrict__ bondB,
    float* __restrict__ h)
{
    __shared__ __align__(16) float h_t[HID][NPG];      // [col][node] 8KB
    __shared__ __align__(16) float agg_t[HID][20];     // [col][node], padded 10KB
    __shared__ __align__(16) float A_s[NPG][HID];      // row-major for phase2
    __shared__ __align__(16) float B_s[NPG][HID];
    __shared__ __align__(16) float Al_s[NPG][HID];
    __shared__ __align__(16) float Bl_s[NPG][HID];
    __shared__ float d2m[NPG][NPG];
    __shared__ unsigned msk[NPG];
    __shared__ float px[NPG], py[NPG], pz[NPG];
    __shared__ int llist[NPG][2];
    __shared__ int lcnt[NPG];
    __shared__ int lsrc_s[EL_PER_G], ltr_s[EL_PER_G], ltp_s[EL_PER_G];

    const int g = blockIdx.x;
    const int tid = threadIdx.x;

    for (int idx = tid; idx < NPG*HID; idx += 256) {
        int n = idx >> 7, cc = idx & 127;
        h_t[cc][n] = h[(size_t)g*NPG*HID + idx];
    }
    if (tid < NPG) {
        px[tid] = pos[(g*NPG + tid)*3 + 0];
        py[tid] = pos[(g*NPG + tid)*3 + 1];
        pz[tid] = pos[(g*NPG + tid)*3 + 2];
        lcnt[tid] = 0; msk[tid] = 0u;
    }
    __syncthreads();
    if (tid < EG_PER_G) {
        int e = g*EG_PER_G + tid;
        int s = eig[e] - g*NPG;
        int d = eig[EG_TOT + e] - g*NPG;
        float dx = px[s]-px[d], dy = py[s]-py[d], dz = pz[s]-pz[d];
        d2m[d][s] = dx*dx + dy*dy + dz*dz;
        atomicOr(&msk[d], 1u << s);
    }
    if (tid < EL_PER_G) {
        int e = g*EL_PER_G + tid;
        int s = eil[e] - g*NPG;
        int d = eil[EL_TOT + e] - g*NPG;
        lsrc_s[tid] = s;
        ltr_s[tid] = clampT(etr[e]);
        ltp_s[tid] = clampT(etp[e]);
        int slot = atomicAdd(&lcnt[d], 1);
        if (slot < 2) llist[d][slot] = tid;
    }
    __syncthreads();

    const int u  = tid & 63;     // column pair: cols 2u, 2u+1
    const int ng = tid >> 6;     // node group: nodes 4ng..4ng+3
    const int c  = tid & 127;    // phase-2 column
    const int dh = tid >> 7;     // phase-2 node half

    for (int l = 0; l < NLAYER; l++) {
        const float* WgL = Wg + (size_t)l*257*HID;
        const float* WlL = Wl + (size_t)l*512*HID;
        const float* WnL = Wn + (size_t)l*256*HID;

        // ---- phase 1: A=h@Wg0, B=h@Wg1+bg, Al=h@Wl0, Bl=h@Wl1
        {
            const float2* wg0 = (const float2*)WgL + u;
            const float2* wg1 = (const float2*)(WgL + 128*HID) + u;
            const float2* wl0 = (const float2*)WlL + u;
            const float2* wl1 = (const float2*)(WlL + 128*HID) + u;
            float2 bgv = *(const float2*)&bg[l*HID + 2*u];
            float2 aA[4], aB[4], aAl[4], aBl[4];
            #pragma unroll
            for (int i = 0; i < 4; i++) {
                aA[i]  = make_float2(0.f, 0.f);
                aB[i]  = bgv;
                aAl[i] = make_float2(0.f, 0.f);
                aBl[i] = make_float2(0.f, 0.f);
            }
            #pragma unroll 4
            for (int k = 0; k < HID; k++) {
                float2 w0 = wg0[k*64];
                float2 w1 = wg1[k*64];
                float2 w2 = wl0[k*64];
                float2 w3 = wl1[k*64];
                float4 hv = *(const float4*)&h_t[k][ng*4];   // wave-uniform broadcast
                float hh[4] = {hv.x, hv.y, hv.z, hv.w};
                #pragma unroll
                for (int i = 0; i < 4; i++) {
                    aA[i].x  = fmaf(hh[i], w0.x, aA[i].x);  aA[i].y  = fmaf(hh[i], w0.y, aA[i].y);
                    aB[i].x  = fmaf(hh[i], w1.x, aB[i].x);  aB[i].y  = fmaf(hh[i], w1.y, aB[i].y);
                    aAl[i].x = fmaf(hh[i], w2.x, aAl[i].x); aAl[i].y = fmaf(hh[i], w2.y, aAl[i].y);
                    aBl[i].x = fmaf(hh[i], w3.x, aBl[i].x); aBl[i].y = fmaf(hh[i], w3.y, aBl[i].y);
                }
            }
            #pragma unroll
            for (int i = 0; i < 4; i++) {
                int n = ng*4 + i;
                *(float2*)&A_s[n][2*u]  = aA[i];
                *(float2*)&B_s[n][2*u]  = aB[i];
                *(float2*)&Al_s[n][2*u] = aAl[i];
                *(float2*)&Bl_s[n][2*u] = aBl[i];
            }
        }
        __syncthreads();

        // ---- phase 2: messages + per-dest accumulation
        {
            float wgd = WgL[256*HID + c];
            const float* bA = bondA + (size_t)l*TMAX*HID;
            const float* bB = bondB + (size_t)l*TMAX*HID;
            float Areg[NPG];
            #pragma unroll
            for (int s = 0; s < NPG; s++) Areg[s] = A_s[s][c];
            #pragma unroll
            for (int dd = 0; dd < 8; dd++) {
                int d = dh*8 + dd;
                float base = B_s[d][c];          // bg already folded in
                unsigned m = msk[d];             // wave-uniform
                float acc = 0.f;
                #pragma unroll
                for (int s = 0; s < NPG; s++) {
                    if (m & (1u << s)) {
                        float x = Areg[s] + fmaf(d2m[d][s], wgd, base);
                        acc += silu_f(x);
                    }
                }
                float blb = Bl_s[d][c];
                int lc2 = lcnt[d] < 2 ? lcnt[d] : 2;
                for (int i2 = 0; i2 < lc2; i2++) {
                    int ke = llist[d][i2];
                    float x = Al_s[lsrc_s[ke]][c] + blb
                            + bA[ltr_s[ke]*HID + c] + bB[ltp_s[ke]*HID + c];
                    acc += silu_f(x);
                }
                agg_t[c][d] = acc;
            }
        }
        __syncthreads();

        // ---- phase 3: h += silu([h,agg]@Wn + bn)
        {
            const float2* wn0 = (const float2*)WnL + u;
            const float2* wn1 = (const float2*)(WnL + 128*HID) + u;
            float2 bnv = *(const float2*)&bn[l*HID + 2*u];
            float2 acc2[4];
            #pragma unroll
            for (int i = 0; i < 4; i++) acc2[i] = bnv;
            #pragma unroll 4
            for (int k = 0; k < HID; k++) {
                float2 w0 = wn0[k*64];
                float2 w1 = wn1[k*64];
                float4 hv = *(const float4*)&h_t[k][ng*4];
                float4 av = *(const float4*)&agg_t[k][ng*4];
                float hh[4] = {hv.x, hv.y, hv.z, hv.w};
                float aa[4] = {av.x, av.y, av.z, av.w};
                #pragma unroll
                for (int i = 0; i < 4; i++) {
                    acc2[i].x = fmaf(hh[i], w0.x, acc2[i].x);
                    acc2[i].y = fmaf(hh[i], w0.y, acc2[i].y);
                    acc2[i].x = fmaf(aa[i], w1.x, acc2[i].x);
                    acc2[i].y = fmaf(aa[i], w1.y, acc2[i].y);
                }
            }
            float2 uo[4];
            #pragma unroll
            for (int i = 0; i < 4; i++) {
                uo[i].x = silu_f(acc2[i].x);
                uo[i].y = silu_f(acc2[i].y);
            }
            __syncthreads();   // all GEMM reads of h_t done before residual update
            #pragma unroll
            for (int i = 0; i < 4; i++) {
                h_t[2*u][ng*4 + i]   += uo[i].x;
                h_t[2*u+1][ng*4 + i] += uo[i].y;
            }
        }
        __syncthreads();
    }

    for (int idx = tid; idx < NPG*HID; idx += 256) {
        int n = idx >> 7, cc = idx & 127;
        h[(size_t)g*NPG*HID + idx] = h_t[cc][n];
    }
}

// Edge MLP: x0=relu((h[s]*h[d])@W00 + pairT); x1=relu(x0@W1+b1); out=x1@W2+b2
__global__ void __launch_bounds__(256) k_mlp(
    const float* __restrict__ h,
    const int* __restrict__ eig, const int* __restrict__ egr, const int* __restrict__ egp,
    const float* __restrict__ pairT, const float* __restrict__ W0,
    const float* __restrict__ W1, const float* __restrict__ b1,
    const float* __restrict__ W2, const float* __restrict__ b2,
    float* __restrict__ out)
{
    __shared__ __align__(16) float h_s[NPG][HID];      // row-major, 8KB
    __shared__ __align__(16) float prod_t[HID][20];    // [col][edge], padded, 10KB
    __shared__ __align__(16) float x0_t[HID][20];      // [col][edge], padded, 10KB
    __shared__ int sgl[EG_PER_G], dgl[EG_PER_G], pidx[EG_PER_G];

    const int g = blockIdx.x;
    const int tid = threadIdx.x;

    for (int idx = tid; idx < NPG*HID; idx += 256)
        h_s[idx >> 7][idx & 127] = h[(size_t)g*NPG*HID + idx];
    if (tid < EG_PER_G) {
        int e = g*EG_PER_G + tid;
        sgl[tid] = eig[e] - g*NPG;
        dgl[tid] = eig[EG_TOT + e] - g*NPG;
        pidx[tid] = clampT(egr[e])*TMAX + clampT(egp[e]);
    }
    __syncthreads();

    const int u  = tid & 63;    // x0: col pair 2u,2u+1 ; x1: col j=u
    const int eg = tid >> 6;    // edge subgroup of 4
    const int kk = tid & 127;   // prod phase col
    const int eh = tid >> 7;    // prod phase edge half
    const float b2v = b2[0];
    const float b1v = b1[u];
    const float w2v = W2[u];

    for (int e0 = 0; e0 < EG_PER_G; e0 += 16) {
        // ---- prod: prod_t[k][e] = h[s_e][k]*h[d_e][k]
        #pragma unroll
        for (int i = 0; i < 8; i++) {
            int e = e0 + eh*8 + i;
            prod_t[kk][eh*8 + i] = h_s[sgl[e]][kk] * h_s[dgl[e]][kk];
        }
        __syncthreads();

        // ---- x0 GEMM: 16 edges x 128 cols over k=128
        float2 acc[4];
        #pragma unroll
        for (int i = 0; i < 4; i++)
            acc[i] = ((const float2*)(pairT + (size_t)pidx[e0 + eg*4 + i]*HID))[u];
        {
            const float2* w0p = (const float2*)W0 + u;
            #pragma unroll 4
            for (int k = 0; k < HID; k++) {
                float2 w = w0p[k*64];
                float4 pv = *(const float4*)&prod_t[k][eg*4];  // broadcast
                float pp[4] = {pv.x, pv.y, pv.z, pv.w};
                #pragma unroll
                for (int i = 0; i < 4; i++) {
                    acc[i].x = fmaf(pp[i], w.x, acc[i].x);
                    acc[i].y = fmaf(pp[i], w.y, acc[i].y);
                }
            }
        }
        #pragma unroll
        for (int i = 0; i < 4; i++) {
            x0_t[2*u][eg*4 + i]   = fmaxf(acc[i].x, 0.f);
            x0_t[2*u+1][eg*4 + i] = fmaxf(acc[i].y, 0.f);
        }
        __syncthreads();

        // ---- x1 GEMM + final dot
        float y[4] = {b1v, b1v, b1v, b1v};
        {
            const float* w1p = W1 + u;
            #pragma unroll 4
            for (int k = 0; k < HID; k++) {
                float wv = w1p[k*64];
                float4 xv = *(const float4*)&x0_t[k][eg*4];    // broadcast
                y[0] = fmaf(xv.x, wv, y[0]);
                y[1] = fmaf(xv.y, wv, y[1]);
                y[2] = fmaf(xv.z, wv, y[2]);
                y[3] = fmaf(xv.w, wv, y[3]);
            }
        }
        #pragma unroll
        for (int i = 0; i < 4; i++) {
            float v = fmaxf(y[i], 0.f) * w2v;
            #pragma unroll
            for (int off = 32; off; off >>= 1)
                v += __shfl_xor(v, off, 64);
            if (u == 0) out[(size_t)g*EG_PER_G + e0 + eg*4 + i] = v + b2v;
        }
        __syncthreads();
    }
}

extern "C" void kernel_launch(void* const* d_in, const int* in_sizes, int n_in,
                              void* d_out, int out_size, void* d_ws, size_t ws_size,
                              hipStream_t stream) {
    const int*   atom_type = (const int*)  d_in[0];
    const float* r_feat    = (const float*)d_in[1];
    const float* p_feat    = (const float*)d_in[2];
    const float* pos       = (const float*)d_in[3];
    const int*   eil       = (const int*)  d_in[4];
    const int*   etr       = (const int*)  d_in[5];
    const int*   etp       = (const int*)  d_in[6];
    const int*   eig       = (const int*)  d_in[7];
    const int*   egr       = (const int*)  d_in[8];
    const int*   egp       = (const int*)  d_in[9];
    const float* bond_emb  = (const float*)d_in[10];
    const float* atom_emb  = (const float*)d_in[11];
    const float* afW       = (const float*)d_in[12];
    const float* Wl        = (const float*)d_in[13];
    const float* bl        = (const float*)d_in[14];
    const float* Wg        = (const float*)d_in[15];
    const float* bg        = (const float*)d_in[16];
    const float* Wn        = (const float*)d_in[17];
    const float* bn        = (const float*)d_in[18];
    const float* W0        = (const float*)d_in[19];
    const float* b0        = (const float*)d_in[20];
    const float* W1        = (const float*)d_in[21];
    const float* b1        = (const float*)d_in[22];
    const float* W2        = (const float*)d_in[23];
    const float* b2        = (const float*)d_in[24];

    float* h     = (float*)d_ws;
    float* bondA = h + (size_t)NNODES*HID;
    float* bondB = bondA + (size_t)NLAYER*TMAX*HID;
    float* pairT = bondB + (size_t)NLAYER*TMAX*HID;
    float* out   = (float*)d_out;

    k_tab_bond<<<dim3(NLAYER*TMAX), dim3(HID), 0, stream>>>(bond_emb, Wl, bl, bondA, bondB);
    k_tab_pair<<<dim3(TMAX*TMAX),  dim3(HID), 0, stream>>>(bond_emb, W0, b0, pairT);
    k_init_h  <<<dim3(NNODES/4),   dim3(256), 0, stream>>>(atom_type, r_feat, p_feat, atom_emb, afW, h);
    k_encoder <<<dim3(G_GRAPHS),   dim3(256), 0, stream>>>(pos, eil, etr, etp, eig,
                                                           Wg, bg, Wl, Wn, bn, bondA, bondB, h);
    k_mlp     <<<dim3(G_GRAPHS),   dim3(256), 0, stream>>>(h, eig, egr, egp, pairT,
                                                           W0, W1, b1, W2, b2, out);
}